// Round 1
// baseline (3170.118 us; speedup 1.0000x reference)
//
#include <hip/hip_runtime.h>
#include <cstddef>

// ---------------------------------------------------------------------------
// TransformerNet: 4-layer GATv2 GNN on MI355X.
//   h = x @ emb_W + emb_b
//   4x GATv2 (self-loops added, softmax over incoming edges per dst)
//   pooled = segment_sum(h[ground_node], batch_idx, 64); out = pooled @ out_W + out_b
// Design: CSR-by-dst per layer (no float atomics in aggregation), one wave per
// dst node, fused softmax (m,s in registers). fp32 everywhere this round.
// ---------------------------------------------------------------------------

// ---------------- embed GEMM: h[n,128] = x[n,32] @ W[32,128] + b -----------
__global__ __launch_bounds__(256) void embed_gemm_kernel(
    const float* __restrict__ x, const float* __restrict__ W,
    const float* __restrict__ b, float* __restrict__ h, int n)
{
  int col  = threadIdx.x & 127;
  int half = threadIdx.x >> 7;
  int r = blockIdx.x * 2 + half;
  if (r >= n) return;
  const float* xrow = x + (size_t)r * 32;
  float acc = b[col];
#pragma unroll
  for (int k = 0; k < 32; ++k)
    acc += xrow[k] * W[k * 128 + col];
  h[(size_t)r * 128 + col] = acc;
}

// ------------- layer GEMM: xl = h@Wl, xr = h@Wr  (h:[n,128], W:[128,128]) --
// threads 0..127 -> Wl col(tid); threads 128..255 -> Wr col(tid-128).
// Each thread caches its W column in 128 VGPRs; h rows staged in LDS.
#define GEMM_ROWS 64
__global__ __launch_bounds__(256) void layer_gemm_kernel(
    const float* __restrict__ h, const float* __restrict__ Wl,
    const float* __restrict__ Wr, float* __restrict__ xl,
    float* __restrict__ xr, int n)
{
  __shared__ float hs[GEMM_ROWS * 128];
  int tid = threadIdx.x;
  int col = tid & 127;
  const float* __restrict__ W = (tid < 128) ? Wl : Wr;   // wave-uniform
  float* __restrict__ out     = (tid < 128) ? xl : xr;

  float wc[128];
#pragma unroll
  for (int k = 0; k < 128; ++k) wc[k] = W[k * 128 + col];

  int row0  = blockIdx.x * GEMM_ROWS;
  int nrows = n - row0; if (nrows > GEMM_ROWS) nrows = GEMM_ROWS;

  const float4* __restrict__ src4 = (const float4*)(h + (size_t)row0 * 128);
  float4* hs4 = (float4*)hs;
  int tot4 = nrows * 32;
  for (int t = tid; t < tot4; t += 256) hs4[t] = src4[t];
  __syncthreads();

  int r = 0;
  for (; r + 4 <= nrows; r += 4) {
    float acc0 = 0.f, acc1 = 0.f, acc2 = 0.f, acc3 = 0.f;
    const float4* h0 = (const float4*)(hs + (r + 0) * 128);
    const float4* h1 = (const float4*)(hs + (r + 1) * 128);
    const float4* h2 = (const float4*)(hs + (r + 2) * 128);
    const float4* h3 = (const float4*)(hs + (r + 3) * 128);
#pragma unroll
    for (int k4 = 0; k4 < 32; ++k4) {
      float4 a = h0[k4], bb = h1[k4], c = h2[k4], d = h3[k4];
      float w0 = wc[4 * k4 + 0], w1 = wc[4 * k4 + 1];
      float w2 = wc[4 * k4 + 2], w3 = wc[4 * k4 + 3];
      acc0 += a.x  * w0 + a.y  * w1 + a.z  * w2 + a.w  * w3;
      acc1 += bb.x * w0 + bb.y * w1 + bb.z * w2 + bb.w * w3;
      acc2 += c.x  * w0 + c.y  * w1 + c.z  * w2 + c.w  * w3;
      acc3 += d.x  * w0 + d.y  * w1 + d.z  * w2 + d.w  * w3;
    }
    out[(size_t)(row0 + r + 0) * 128 + col] = acc0;
    out[(size_t)(row0 + r + 1) * 128 + col] = acc1;
    out[(size_t)(row0 + r + 2) * 128 + col] = acc2;
    out[(size_t)(row0 + r + 3) * 128 + col] = acc3;
  }
  for (; r < nrows; ++r) {   // tail (unused for n % 4 == 0, kept for safety)
    float acc = 0.f;
    const float* hr = hs + r * 128;
#pragma unroll
    for (int k = 0; k < 128; ++k) acc += hr[k] * wc[k];
    out[(size_t)(row0 + r) * 128 + col] = acc;
  }
}

// ---------------- CSR build ------------------------------------------------
__global__ __launch_bounds__(256) void deg_init_kernel(int* __restrict__ deg, int n)
{
  int i = blockIdx.x * 256 + threadIdx.x;
  if (i < n) deg[i] = 1;                    // self-loop
}

__global__ __launch_bounds__(256) void edge_count_kernel(
    const int* __restrict__ dst, int E, int* __restrict__ deg)
{
  int e = blockIdx.x * 256 + threadIdx.x;
  if (e < E) atomicAdd(&deg[dst[e]], 1);
}

// single-block exclusive scan, 1024 threads, Hillis-Steele per chunk
__global__ __launch_bounds__(1024) void scan_kernel(
    const int* __restrict__ deg, int* __restrict__ offs, int n)
{
  __shared__ int buf[1024];
  __shared__ int carry;
  int tid = threadIdx.x;
  if (tid == 0) carry = 0;
  __syncthreads();
  for (int base = 0; base < n; base += 1024) {
    int i = base + tid;
    int v = (i < n) ? deg[i] : 0;
    buf[tid] = v;
    __syncthreads();
#pragma unroll
    for (int d = 1; d < 1024; d <<= 1) {
      int t = (tid >= d) ? buf[tid - d] : 0;
      __syncthreads();
      buf[tid] += t;
      __syncthreads();
    }
    int incl = buf[tid];
    int c = carry;
    if (i < n) offs[i] = c + incl - v;      // exclusive
    __syncthreads();
    if (tid == 1023) carry = c + buf[1023];
    __syncthreads();
  }
  if (tid == 0) offs[n] = carry;
}

__global__ __launch_bounds__(256) void cursor_init_kernel(
    const int* __restrict__ offs, int* __restrict__ cur, int n)
{
  int i = blockIdx.x * 256 + threadIdx.x;
  if (i < n) cur[i] = offs[i];
}

__global__ __launch_bounds__(256) void fill_kernel(
    const int* __restrict__ src, const int* __restrict__ dst, int E, int n,
    int* __restrict__ cur, int* __restrict__ csr)
{
  int id = blockIdx.x * 256 + threadIdx.x;
  if (id >= E + n) return;
  int s, d;
  if (id < E) { s = src[id]; d = dst[id]; }
  else        { s = id - E;  d = s; }       // self-loop
  int slot = atomicAdd(&cur[d], 1);
  csr[slot] = s;
}

// ---------------- fused GATv2 edge phase: one wave per dst node ------------
__global__ __launch_bounds__(256) void gat_dst_kernel(
    const float* __restrict__ xl, const float* __restrict__ xr,
    const int* __restrict__ offs, const int* __restrict__ csr,
    const float* __restrict__ att, const float* __restrict__ bias,
    float* __restrict__ hout, int n)
{
  int wid  = (blockIdx.x * 256 + threadIdx.x) >> 6;
  int lane = threadIdx.x & 63;
  if (wid >= n) return;
  int v = wid;

  float2 xrv = *(const float2*)(xr + (size_t)v * 128 + lane * 2);
  float a0 = att[lane * 2], a1 = att[lane * 2 + 1];
  int beg = offs[v], end = offs[v + 1];

  // pass 1: max of edge scores
  float m = -3.4e38f;
  for (int j = beg; j < end; ++j) {
    int s = csr[j];
    float2 xls = *(const float2*)(xl + (size_t)s * 128 + lane * 2);
    float t0 = xls.x + xrv.x; t0 = t0 > 0.f ? t0 : 0.2f * t0;
    float t1 = xls.y + xrv.y; t1 = t1 > 0.f ? t1 : 0.2f * t1;
    float part = t0 * a0 + t1 * a1;
#pragma unroll
    for (int o = 32; o >= 1; o >>= 1) part += __shfl_xor(part, o, 64);
    m = fmaxf(m, part);
  }

  // pass 2: softmax-weighted aggregation
  float ssum = 0.f, acc0 = 0.f, acc1 = 0.f;
  for (int j = beg; j < end; ++j) {
    int s = csr[j];
    float2 xls = *(const float2*)(xl + (size_t)s * 128 + lane * 2);
    float t0 = xls.x + xrv.x; t0 = t0 > 0.f ? t0 : 0.2f * t0;
    float t1 = xls.y + xrv.y; t1 = t1 > 0.f ? t1 : 0.2f * t1;
    float part = t0 * a0 + t1 * a1;
#pragma unroll
    for (int o = 32; o >= 1; o >>= 1) part += __shfl_xor(part, o, 64);
    float p = __expf(part - m);
    ssum += p;
    acc0 += p * xls.x;
    acc1 += p * xls.y;
  }
  float inv = 1.0f / ssum;
  float b0 = bias[lane * 2], b1 = bias[lane * 2 + 1];
  float2 o2 = make_float2(acc0 * inv + b0, acc1 * inv + b1);
  *(float2*)(hout + (size_t)v * 128 + lane * 2) = o2;
}

// ---------------- pooling + output GEMM ------------------------------------
__global__ __launch_bounds__(256) void zero_kernel(float* __restrict__ p, int n)
{
  int i = blockIdx.x * 256 + threadIdx.x;
  if (i < n) p[i] = 0.f;
}

__global__ __launch_bounds__(256) void pool_kernel(
    const float* __restrict__ h, const int* __restrict__ gnode,
    const int* __restrict__ bidx, float* __restrict__ pooled, int ng)
{
  __shared__ float acc[64 * 128];           // 32 KiB
  int tid = threadIdx.x;
  for (int t = tid; t < 64 * 128; t += 256) acc[t] = 0.f;
  __syncthreads();
  int col = tid & 127, half = tid >> 7;
  for (int nd = blockIdx.x * 2 + half; nd < ng; nd += gridDim.x * 2) {
    int row = gnode[nd];
    int g   = bidx[nd];
    atomicAdd(&acc[g * 128 + col], h[(size_t)row * 128 + col]);
  }
  __syncthreads();
  for (int t = tid; t < 64 * 128; t += 256) atomicAdd(&pooled[t], acc[t]);
}

__global__ __launch_bounds__(256) void out_gemm_kernel(
    const float* __restrict__ pooled, const float* __restrict__ W,
    const float* __restrict__ b, float* __restrict__ out)
{
  int id = blockIdx.x * 256 + threadIdx.x;
  if (id >= 64 * 16) return;
  int g = id >> 4, f = id & 15;
  float acc = b[f];
#pragma unroll
  for (int k = 0; k < 128; ++k)
    acc += pooled[g * 128 + k] * W[k * 16 + f];
  out[id] = acc;
}

// ---------------------------------------------------------------------------
extern "C" void kernel_launch(void* const* d_in, const int* in_sizes, int n_in,
                              void* d_out, int out_size, void* d_ws, size_t ws_size,
                              hipStream_t stream)
{
  const float* x    = (const float*)d_in[0];
  const int* ei0    = (const int*)d_in[1];   // edge_index            [2,1e6]
  const int* ei_sg  = (const int*)d_in[2];   // subgraph_edge_index   [2,1e6]
  const int* ei_ns  = (const int*)d_in[3];   // node_subnode_index    [2,2e5]
  const int* ei_sn  = (const int*)d_in[4];   // subnode_node_index    [2,2e5]
  const int* gnode  = (const int*)d_in[5];   // ground_node
  // d_in[6] = subgraph_batch_index (unused by reference)
  const int* bidx   = (const int*)d_in[7];   // batch_idx
  const float* embW = (const float*)d_in[8];
  const float* embB = (const float*)d_in[9];
  const float* Wl   = (const float*)d_in[10];
  const float* Wr   = (const float*)d_in[11];
  const float* att  = (const float*)d_in[12];
  const float* bias = (const float*)d_in[13];
  const float* outW = (const float*)d_in[14];
  const float* outB = (const float*)d_in[15];

  const int n  = in_sizes[0] / 32;           // 100000
  const int ng = in_sizes[5];                // 40000

  // reference layer order: edge_index, node_subnode, subgraph_edge, subnode_node
  const int  E_arr[4] = { in_sizes[1] / 2, in_sizes[3] / 2,
                          in_sizes[2] / 2, in_sizes[4] / 2 };
  const int* eptr[4]  = { ei0, ei_ns, ei_sg, ei_sn };
  int Emax = 0;
  for (int i = 0; i < 4; ++i) if (E_arr[i] > Emax) Emax = E_arr[i];

  // workspace carve (bump allocator, 256B aligned)
  char* ws = (char*)d_ws;
  size_t off = 0;
  auto alloc = [&](size_t bytes) -> void* {
    void* p = ws + off;
    off = (off + bytes + 255) & ~(size_t)255;
    return p;
  };
  float* h      = (float*)alloc((size_t)n * 128 * sizeof(float));
  float* xl     = (float*)alloc((size_t)n * 128 * sizeof(float));
  float* xr     = (float*)alloc((size_t)n * 128 * sizeof(float));
  int*   deg    = (int*)alloc((size_t)n * sizeof(int));
  int*   offs   = (int*)alloc((size_t)(n + 1) * sizeof(int));
  int*   cur    = (int*)alloc((size_t)n * sizeof(int));
  int*   csr    = (int*)alloc((size_t)(Emax + n) * sizeof(int));
  float* pooled = (float*)alloc(64 * 128 * sizeof(float));
  (void)ws_size; (void)n_in; (void)out_size;

  embed_gemm_kernel<<<(n + 1) / 2, 256, 0, stream>>>(x, embW, embB, h, n);

  for (int l = 0; l < 4; ++l) {
    const int E = E_arr[l];
    const int* src = eptr[l];
    const int* dst = eptr[l] + E;

    layer_gemm_kernel<<<(n + GEMM_ROWS - 1) / GEMM_ROWS, 256, 0, stream>>>(
        h, Wl + (size_t)l * 128 * 128, Wr + (size_t)l * 128 * 128, xl, xr, n);

    deg_init_kernel<<<(n + 255) / 256, 256, 0, stream>>>(deg, n);
    edge_count_kernel<<<(E + 255) / 256, 256, 0, stream>>>(dst, E, deg);
    scan_kernel<<<1, 1024, 0, stream>>>(deg, offs, n);
    cursor_init_kernel<<<(n + 255) / 256, 256, 0, stream>>>(offs, cur, n);
    fill_kernel<<<(E + n + 255) / 256, 256, 0, stream>>>(src, dst, E, n, cur, csr);

    gat_dst_kernel<<<((size_t)n * 64 + 255) / 256, 256, 0, stream>>>(
        xl, xr, offs, csr, att + (size_t)l * 128, bias + (size_t)l * 128, h, n);
  }

  zero_kernel<<<(64 * 128 + 255) / 256, 256, 0, stream>>>(pooled, 64 * 128);
  pool_kernel<<<64, 256, 0, stream>>>(h, gnode, bidx, pooled, ng);
  out_gemm_kernel<<<4, 256, 0, stream>>>(pooled, outW, outB, (float*)d_out);
}

// Round 2
// 1189.638 us; speedup vs baseline: 2.6648x; 2.6648x over previous
//
#include <hip/hip_runtime.h>
#include <cstddef>

// ---------------------------------------------------------------------------
// TransformerNet: 4-layer GATv2 GNN on MI355X (gfx950).
// R2: bf16 MFMA layer-GEMMs (B frags resident in VGPRs, A frags straight from
// global — no LDS), single-pass softmax (no max subtraction; e is O(30) max),
// 3-phase multi-block scan for CSR offsets.
// ---------------------------------------------------------------------------

typedef __attribute__((ext_vector_type(8))) short bf16x8;  // 8 bf16 = 4 VGPR
typedef __attribute__((ext_vector_type(4))) float f32x4;

__device__ __forceinline__ unsigned short f2bf(float f) {
  unsigned int u = __float_as_uint(f);
  u += 0x7fffu + ((u >> 16) & 1u);            // round-to-nearest-even
  return (unsigned short)(u >> 16);
}

// ---------------- embed GEMM: hb[n,128](bf16) = x[n,32] @ W[32,128] + b ----
__global__ __launch_bounds__(256) void embed_gemm_kernel(
    const float* __restrict__ x, const float* __restrict__ W,
    const float* __restrict__ b, unsigned short* __restrict__ hb, int n)
{
  int col  = threadIdx.x & 127;
  int half = threadIdx.x >> 7;
  int r = blockIdx.x * 2 + half;
  if (r >= n) return;
  const float* xrow = x + (size_t)r * 32;
  float acc = b[col];
#pragma unroll
  for (int k = 0; k < 32; ++k)
    acc += xrow[k] * W[k * 128 + col];
  hb[(size_t)r * 128 + col] = f2bf(acc);
}

// ---------------- W pack: B-fragment layout, bf16 --------------------------
// packB[layer][ct=16][kt=4][lane=64][j=8]; element = W[k][col],
// k = kt*32 + (lane>>4)*8 + j, col = ct*16 + (lane&15); ct<8 -> Wl, else Wr.
__global__ __launch_bounds__(256) void pack_w_kernel(
    const float* __restrict__ Wl, const float* __restrict__ Wr,
    unsigned short* __restrict__ packB)
{
  int id = blockIdx.x * 256 + threadIdx.x;   // 4*16*4*64*8 = 131072
  if (id >= 131072) return;
  int j    = id & 7;
  int lane = (id >> 3) & 63;
  int kt   = (id >> 9) & 3;
  int ct   = (id >> 11) & 15;
  int l    = id >> 15;
  int k    = kt * 32 + (lane >> 4) * 8 + j;
  int col  = ct * 16 + (lane & 15);
  float v = (ct < 8) ? Wl[(size_t)l * 16384 + k * 128 + col]
                     : Wr[(size_t)l * 16384 + k * 128 + (col - 128)];
  packB[id] = f2bf(v);
}

// ------------- layer GEMM (MFMA): [xl|xr][n,128] = hb[n,128] @ packB -------
// 4 waves/block; wave w owns 64 cols (4 col-tiles). B frags in VGPRs for the
// whole kernel; A frags loaded directly from global (row-major bf16 rows).
__global__ __launch_bounds__(256) void gemm_mfma_kernel(
    const unsigned short* __restrict__ hb,
    const unsigned short* __restrict__ packB,   // this layer's [16][4][64][8]
    float* __restrict__ xl, float* __restrict__ xr, int n)
{
  const int wave = threadIdx.x >> 6;
  const int lane = threadIdx.x & 63;
  const int rlan = lane & 15;        // A row within tile / C col within tile
  const int kgrp = lane >> 4;        // 0..3

  bf16x8 Bf[4][4];
#pragma unroll
  for (int ct = 0; ct < 4; ++ct)
#pragma unroll
    for (int kt = 0; kt < 4; ++kt)
      Bf[ct][kt] = *(const bf16x8*)(packB +
          ((((size_t)(wave * 4 + ct)) * 4 + kt) * 64 + lane) * 8);

  float* __restrict__ outp = (wave < 2) ? xl : xr;   // wave-uniform
  const int colbase = (wave & 1) * 64;

  const int ntiles = (n + 31) / 32;
  for (int tile = blockIdx.x; tile < ntiles; tile += gridDim.x) {
    const int row0 = tile * 32;
    bf16x8 Af[2][4];
#pragma unroll
    for (int rt = 0; rt < 2; ++rt) {
      int r = row0 + rt * 16 + rlan;
      if (r >= n) r = n - 1;                    // clamp (tail safety)
      const unsigned short* ap = hb + (size_t)r * 128 + kgrp * 8;
#pragma unroll
      for (int kt = 0; kt < 4; ++kt)
        Af[rt][kt] = *(const bf16x8*)(ap + kt * 32);
    }
    f32x4 acc[2][4];
#pragma unroll
    for (int rt = 0; rt < 2; ++rt)
#pragma unroll
      for (int ct = 0; ct < 4; ++ct)
        acc[rt][ct] = (f32x4){0.f, 0.f, 0.f, 0.f};
#pragma unroll
    for (int kt = 0; kt < 4; ++kt)
#pragma unroll
      for (int rt = 0; rt < 2; ++rt)
#pragma unroll
        for (int ct = 0; ct < 4; ++ct)
          acc[rt][ct] = __builtin_amdgcn_mfma_f32_16x16x32_bf16(
              Af[rt][kt], Bf[ct][kt], acc[rt][ct], 0, 0, 0);
    // C/D: col = lane&15, row = kgrp*4 + reg   [dtype-independent, verified]
#pragma unroll
    for (int rt = 0; rt < 2; ++rt) {
      int rowb = row0 + rt * 16 + kgrp * 4;
#pragma unroll
      for (int ct = 0; ct < 4; ++ct) {
        int col = colbase + ct * 16 + rlan;
        size_t base = (size_t)rowb * 128 + col;
#pragma unroll
        for (int r = 0; r < 4; ++r)
          if (rowb + r < n) outp[base + (size_t)r * 128] = acc[rt][ct][r];
      }
    }
  }
}

// ---------------- CSR build ------------------------------------------------
__global__ __launch_bounds__(256) void deg_init_kernel(int* __restrict__ deg, int n)
{
  int i = blockIdx.x * 256 + threadIdx.x;
  if (i < n) deg[i] = 1;                    // self-loop
}

__global__ __launch_bounds__(256) void edge_count_kernel(
    const int* __restrict__ dst, int E, int* __restrict__ deg)
{
  int e = blockIdx.x * 256 + threadIdx.x;
  if (e < E) atomicAdd(&deg[dst[e]], 1);
}

// 3-phase exclusive scan of deg[0..n) -> offs, cur; offs[n] = total.
__global__ __launch_bounds__(1024) void scan_phase1(
    const int* __restrict__ deg, int* __restrict__ incl,
    int* __restrict__ bsum, int n)
{
  __shared__ int buf[1024];
  int tid = threadIdx.x;
  int i = blockIdx.x * 1024 + tid;
  int v = (i < n) ? deg[i] : 0;
  buf[tid] = v;
  __syncthreads();
#pragma unroll
  for (int d = 1; d < 1024; d <<= 1) {
    int t = (tid >= d) ? buf[tid - d] : 0;
    __syncthreads();
    buf[tid] += t;
    __syncthreads();
  }
  if (i < n) incl[i] = buf[tid];
  if (tid == 1023) bsum[blockIdx.x] = buf[1023];
}

__global__ __launch_bounds__(128) void scan_phase2(
    int* __restrict__ bsum, int nb, int* __restrict__ offs_n)
{
  __shared__ int buf[128];
  int tid = threadIdx.x;
  int v = (tid < nb) ? bsum[tid] : 0;
  buf[tid] = v;
  __syncthreads();
#pragma unroll
  for (int d = 1; d < 128; d <<= 1) {
    int t = (tid >= d) ? buf[tid - d] : 0;
    __syncthreads();
    buf[tid] += t;
    __syncthreads();
  }
  if (tid < nb) bsum[tid] = buf[tid] - v;   // exclusive
  if (tid == 127) *offs_n = buf[127];
}

__global__ __launch_bounds__(256) void scan_phase3(
    const int* __restrict__ incl, const int* __restrict__ deg,
    const int* __restrict__ bsum, int* __restrict__ offs,
    int* __restrict__ cur, int n)
{
  int i = blockIdx.x * 256 + threadIdx.x;
  if (i < n) {
    int e = incl[i] - deg[i] + bsum[i >> 10];
    offs[i] = e;
    cur[i] = e;
  }
}

__global__ __launch_bounds__(256) void fill_kernel(
    const int* __restrict__ src, const int* __restrict__ dst, int E, int n,
    int* __restrict__ cur, int* __restrict__ csr)
{
  int id = blockIdx.x * 256 + threadIdx.x;
  if (id >= E + n) return;
  int s, d;
  if (id < E) { s = src[id]; d = dst[id]; }
  else        { s = id - E;  d = s; }       // self-loop
  int slot = atomicAdd(&cur[d], 1);
  csr[slot] = s;
}

// ---------------- fused GATv2 edge phase: one wave per dst node ------------
// Single pass: no max subtraction (e is O(±30); exp cannot overflow fp32;
// softmax is shift-invariant). Writes fp32 h and/or bf16 h per flags.
__global__ __launch_bounds__(256) void gat_dst_kernel(
    const float* __restrict__ xl, const float* __restrict__ xr,
    const int* __restrict__ offs, const int* __restrict__ csr,
    const float* __restrict__ att, const float* __restrict__ bias,
    float* __restrict__ hout_f, unsigned short* __restrict__ hout_b, int n)
{
  int wid  = (blockIdx.x * 256 + threadIdx.x) >> 6;
  int lane = threadIdx.x & 63;
  if (wid >= n) return;
  int v = wid;

  float2 xrv = *(const float2*)(xr + (size_t)v * 128 + lane * 2);
  float a0 = att[lane * 2], a1 = att[lane * 2 + 1];
  int beg = offs[v], end = offs[v + 1];

  float ssum = 0.f, acc0 = 0.f, acc1 = 0.f;
  for (int j = beg; j < end; ++j) {
    int s = csr[j];
    float2 xls = *(const float2*)(xl + (size_t)s * 128 + lane * 2);
    float t0 = xls.x + xrv.x; t0 = t0 > 0.f ? t0 : 0.2f * t0;
    float t1 = xls.y + xrv.y; t1 = t1 > 0.f ? t1 : 0.2f * t1;
    float part = t0 * a0 + t1 * a1;
#pragma unroll
    for (int o = 32; o >= 1; o >>= 1) part += __shfl_xor(part, o, 64);
    float p = __expf(part);
    ssum += p;
    acc0 += p * xls.x;
    acc1 += p * xls.y;
  }
  float inv = 1.0f / ssum;
  float o0 = acc0 * inv + bias[lane * 2];
  float o1 = acc1 * inv + bias[lane * 2 + 1];
  if (hout_f)
    *(float2*)(hout_f + (size_t)v * 128 + lane * 2) = make_float2(o0, o1);
  if (hout_b) {
    unsigned int pk = (unsigned int)f2bf(o0) | ((unsigned int)f2bf(o1) << 16);
    *(unsigned int*)(hout_b + (size_t)v * 128 + lane * 2) = pk;
  }
}

// ---------------- pooling + output GEMM ------------------------------------
__global__ __launch_bounds__(256) void zero_kernel(float* __restrict__ p, int n)
{
  int i = blockIdx.x * 256 + threadIdx.x;
  if (i < n) p[i] = 0.f;
}

__global__ __launch_bounds__(256) void pool_kernel(
    const float* __restrict__ h, const int* __restrict__ gnode,
    const int* __restrict__ bidx, float* __restrict__ pooled, int ng)
{
  __shared__ float acc[64 * 128];           // 32 KiB
  int tid = threadIdx.x;
  for (int t = tid; t < 64 * 128; t += 256) acc[t] = 0.f;
  __syncthreads();
  int col = tid & 127, half = tid >> 7;
  for (int nd = blockIdx.x * 2 + half; nd < ng; nd += gridDim.x * 2) {
    int row = gnode[nd];
    int g   = bidx[nd];
    atomicAdd(&acc[g * 128 + col], h[(size_t)row * 128 + col]);
  }
  __syncthreads();
  for (int t = tid; t < 64 * 128; t += 256) atomicAdd(&pooled[t], acc[t]);
}

__global__ __launch_bounds__(256) void out_gemm_kernel(
    const float* __restrict__ pooled, const float* __restrict__ W,
    const float* __restrict__ b, float* __restrict__ out)
{
  int id = blockIdx.x * 256 + threadIdx.x;
  if (id >= 64 * 16) return;
  int g = id >> 4, f = id & 15;
  float acc = b[f];
#pragma unroll
  for (int k = 0; k < 128; ++k)
    acc += pooled[g * 128 + k] * W[k * 16 + f];
  out[id] = acc;
}

// ---------------------------------------------------------------------------
extern "C" void kernel_launch(void* const* d_in, const int* in_sizes, int n_in,
                              void* d_out, int out_size, void* d_ws, size_t ws_size,
                              hipStream_t stream)
{
  const float* x    = (const float*)d_in[0];
  const int* ei0    = (const int*)d_in[1];   // edge_index            [2,1e6]
  const int* ei_sg  = (const int*)d_in[2];   // subgraph_edge_index   [2,1e6]
  const int* ei_ns  = (const int*)d_in[3];   // node_subnode_index    [2,2e5]
  const int* ei_sn  = (const int*)d_in[4];   // subnode_node_index    [2,2e5]
  const int* gnode  = (const int*)d_in[5];   // ground_node
  // d_in[6] = subgraph_batch_index (unused by reference)
  const int* bidx   = (const int*)d_in[7];   // batch_idx
  const float* embW = (const float*)d_in[8];
  const float* embB = (const float*)d_in[9];
  const float* Wl   = (const float*)d_in[10];
  const float* Wr   = (const float*)d_in[11];
  const float* att  = (const float*)d_in[12];
  const float* bias = (const float*)d_in[13];
  const float* outW = (const float*)d_in[14];
  const float* outB = (const float*)d_in[15];

  const int n  = in_sizes[0] / 32;           // 100000
  const int ng = in_sizes[5];                // 40000

  // reference layer order: edge_index, node_subnode, subgraph_edge, subnode_node
  const int  E_arr[4] = { in_sizes[1] / 2, in_sizes[3] / 2,
                          in_sizes[2] / 2, in_sizes[4] / 2 };
  const int* eptr[4]  = { ei0, ei_ns, ei_sg, ei_sn };
  int Emax = 0;
  for (int i = 0; i < 4; ++i) if (E_arr[i] > Emax) Emax = E_arr[i];

  // workspace carve (bump allocator, 256B aligned)
  char* ws = (char*)d_ws;
  size_t off = 0;
  auto alloc = [&](size_t bytes) -> void* {
    void* p = ws + off;
    off = (off + bytes + 255) & ~(size_t)255;
    return p;
  };
  float*          h      = (float*)alloc((size_t)n * 128 * sizeof(float));
  unsigned short* hb     = (unsigned short*)alloc((size_t)n * 128 * sizeof(unsigned short));
  float*          xl     = (float*)alloc((size_t)n * 128 * sizeof(float));
  float*          xr     = (float*)alloc((size_t)n * 128 * sizeof(float));
  int*            deg    = (int*)alloc((size_t)n * sizeof(int));
  int*            incl   = (int*)alloc((size_t)n * sizeof(int));
  int*            offs   = (int*)alloc((size_t)(n + 1) * sizeof(int));
  int*            cur    = (int*)alloc((size_t)n * sizeof(int));
  int*            bsum   = (int*)alloc(256 * sizeof(int));
  int*            csr    = (int*)alloc((size_t)(Emax + n) * sizeof(int));
  unsigned short* packB  = (unsigned short*)alloc(131072 * sizeof(unsigned short));
  float*          pooled = (float*)alloc(64 * 128 * sizeof(float));
  (void)ws_size; (void)n_in; (void)out_size;

  const int nblk = (n + 1023) / 1024;        // scan blocks (98)

  pack_w_kernel<<<131072 / 256, 256, 0, stream>>>(Wl, Wr, packB);
  embed_gemm_kernel<<<(n + 1) / 2, 256, 0, stream>>>(x, embW, embB, hb, n);

  for (int l = 0; l < 4; ++l) {
    const int E = E_arr[l];
    const int* src = eptr[l];
    const int* dst = eptr[l] + E;

    gemm_mfma_kernel<<<1024, 256, 0, stream>>>(
        hb, packB + (size_t)l * 32768, xl, xr, n);

    deg_init_kernel<<<(n + 255) / 256, 256, 0, stream>>>(deg, n);
    edge_count_kernel<<<(E + 255) / 256, 256, 0, stream>>>(dst, E, deg);
    scan_phase1<<<nblk, 1024, 0, stream>>>(deg, incl, bsum, n);
    scan_phase2<<<1, 128, 0, stream>>>(bsum, nblk, offs + n);
    scan_phase3<<<(n + 255) / 256, 256, 0, stream>>>(incl, deg, bsum, offs, cur, n);
    fill_kernel<<<(E + n + 255) / 256, 256, 0, stream>>>(src, dst, E, n, cur, csr);

    gat_dst_kernel<<<((size_t)n * 64 + 255) / 256, 256, 0, stream>>>(
        xl, xr, offs, csr, att + (size_t)l * 128, bias + (size_t)l * 128,
        (l == 3) ? h : nullptr, (l < 3) ? hb : nullptr, n);
  }

  zero_kernel<<<(64 * 128 + 255) / 256, 256, 0, stream>>>(pooled, 64 * 128);
  pool_kernel<<<64, 256, 0, stream>>>(h, gnode, bidx, pooled, ng);
  out_gemm_kernel<<<4, 256, 0, stream>>>(pooled, outW, outB, (float*)d_out);
}

// Round 3
// 967.140 us; speedup vs baseline: 3.2778x; 1.2301x over previous
//
#include <hip/hip_runtime.h>
#include <cstddef>

// ---------------------------------------------------------------------------
// TransformerNet: 4-layer GATv2 GNN on MI355X (gfx950).
// R3: subgrouped gat_dst (4 edges/iter, 16 lanes/edge, bf16 gathers),
// batched CSR build for all 4 graphs (5 kernels total), bf16 GEMM outputs.
// ---------------------------------------------------------------------------

typedef __attribute__((ext_vector_type(8))) short bf16x8;  // 8 bf16 = 4 VGPR
typedef __attribute__((ext_vector_type(4))) float f32x4;

__device__ __forceinline__ unsigned short f2bf(float f) {
  unsigned int u = __float_as_uint(f);
  u += 0x7fffu + ((u >> 16) & 1u);            // round-to-nearest-even
  return (unsigned short)(u >> 16);
}
__device__ __forceinline__ float bf2f(short s) {
  return __uint_as_float(((unsigned int)(unsigned short)s) << 16);
}

// ---------------- setup: pack W + zero deg4 + zero pooled ------------------
// packB[layer][ct=16][kt=4][lane=64][j=8]; element = W[k][col],
// k = kt*32 + (lane>>4)*8 + j, col = ct*16 + (lane&15); ct<8 -> Wl, else Wr.
__global__ __launch_bounds__(256) void setup_kernel(
    const float* __restrict__ Wl, const float* __restrict__ Wr,
    unsigned short* __restrict__ packB, int* __restrict__ deg4,
    float* __restrict__ pooled, int n)
{
  int id = blockIdx.x * 256 + threadIdx.x;
  if (id < 131072) {
    int j    = id & 7;
    int lane = (id >> 3) & 63;
    int kt   = (id >> 9) & 3;
    int ct   = (id >> 11) & 15;
    int l    = id >> 15;
    int k    = kt * 32 + (lane >> 4) * 8 + j;
    int col  = ct * 16 + (lane & 15);
    float v = (ct < 8) ? Wl[(size_t)l * 16384 + k * 128 + col]
                       : Wr[(size_t)l * 16384 + k * 128 + (col - 128)];
    packB[id] = f2bf(v);
  }
  int z = id - 131072;
  if (z >= 0 && z < 4 * n) deg4[z] = 0;
  int p = z - 4 * n;
  if (p >= 0 && p < 64 * 128) pooled[p] = 0.f;
}

// ---------------- embed GEMM: hb[n,128](bf16) = x[n,32] @ W[32,128] + b ----
__global__ __launch_bounds__(256) void embed_gemm_kernel(
    const float* __restrict__ x, const float* __restrict__ W,
    const float* __restrict__ b, unsigned short* __restrict__ hb, int n)
{
  int col  = threadIdx.x & 127;
  int half = threadIdx.x >> 7;
  int r = blockIdx.x * 2 + half;
  if (r >= n) return;
  const float* xrow = x + (size_t)r * 32;
  float acc = b[col];
#pragma unroll
  for (int k = 0; k < 32; ++k)
    acc += xrow[k] * W[k * 128 + col];
  hb[(size_t)r * 128 + col] = f2bf(acc);
}

// ------------- layer GEMM (MFMA): [xlb|xrb][n,128] = hb @ packB, bf16 out --
__global__ __launch_bounds__(256) void gemm_mfma_kernel(
    const unsigned short* __restrict__ hb,
    const unsigned short* __restrict__ packB,   // this layer's [16][4][64][8]
    unsigned short* __restrict__ xlb, unsigned short* __restrict__ xrb, int n)
{
  const int wave = threadIdx.x >> 6;
  const int lane = threadIdx.x & 63;
  const int rlan = lane & 15;
  const int kgrp = lane >> 4;

  bf16x8 Bf[4][4];
#pragma unroll
  for (int ct = 0; ct < 4; ++ct)
#pragma unroll
    for (int kt = 0; kt < 4; ++kt)
      Bf[ct][kt] = *(const bf16x8*)(packB +
          ((((size_t)(wave * 4 + ct)) * 4 + kt) * 64 + lane) * 8);

  unsigned short* __restrict__ outp = (wave < 2) ? xlb : xrb;  // wave-uniform
  const int colbase = (wave & 1) * 64;

  const int ntiles = (n + 31) / 32;
  for (int tile = blockIdx.x; tile < ntiles; tile += gridDim.x) {
    const int row0 = tile * 32;
    bf16x8 Af[2][4];
#pragma unroll
    for (int rt = 0; rt < 2; ++rt) {
      int r = row0 + rt * 16 + rlan;
      if (r >= n) r = n - 1;
      const unsigned short* ap = hb + (size_t)r * 128 + kgrp * 8;
#pragma unroll
      for (int kt = 0; kt < 4; ++kt)
        Af[rt][kt] = *(const bf16x8*)(ap + kt * 32);
    }
    f32x4 acc[2][4];
#pragma unroll
    for (int rt = 0; rt < 2; ++rt)
#pragma unroll
      for (int ct = 0; ct < 4; ++ct)
        acc[rt][ct] = (f32x4){0.f, 0.f, 0.f, 0.f};
#pragma unroll
    for (int kt = 0; kt < 4; ++kt)
#pragma unroll
      for (int rt = 0; rt < 2; ++rt)
#pragma unroll
        for (int ct = 0; ct < 4; ++ct)
          acc[rt][ct] = __builtin_amdgcn_mfma_f32_16x16x32_bf16(
              Af[rt][kt], Bf[ct][kt], acc[rt][ct], 0, 0, 0);
    // C/D: col = lane&15, row = kgrp*4 + reg
#pragma unroll
    for (int rt = 0; rt < 2; ++rt) {
      int rowb = row0 + rt * 16 + kgrp * 4;
#pragma unroll
      for (int ct = 0; ct < 4; ++ct) {
        int col = colbase + ct * 16 + rlan;
        size_t base = (size_t)rowb * 128 + col;
#pragma unroll
        for (int r = 0; r < 4; ++r)
          if (rowb + r < n) outp[base + (size_t)r * 128] = f2bf(acc[rt][ct][r]);
      }
    }
  }
}

// ---------------- batched CSR build (all 4 graphs at once) -----------------
__global__ __launch_bounds__(256) void count_all_kernel(
    const int* __restrict__ d0, const int* __restrict__ d1,
    const int* __restrict__ d2, const int* __restrict__ d3,
    int e0, int e1, int e2, int e3, int n, int* __restrict__ deg4)
{
  int id = blockIdx.x * 256 + threadIdx.x;
  int t1 = e0, t2 = t1 + e1, t3 = t2 + e2, t4 = t3 + e3;
  if (id >= t4) return;
  int l, e; const int* dp;
  if      (id < t1) { l = 0; e = id;      dp = d0; }
  else if (id < t2) { l = 1; e = id - t1; dp = d1; }
  else if (id < t3) { l = 2; e = id - t2; dp = d2; }
  else              { l = 3; e = id - t3; dp = d3; }
  atomicAdd(&deg4[l * n + dp[e]], 1);
}

// per-layer segmented scan: grid = 4*nblk, block b -> (layer=b/nblk, wb=b%nblk)
__global__ __launch_bounds__(1024) void scan_phase1(
    const int* __restrict__ deg4, int* __restrict__ incl4,
    int* __restrict__ bsum, int n, int nblk)
{
  __shared__ int buf[1024];
  int tid = threadIdx.x;
  int layer = blockIdx.x / nblk;
  int wb    = blockIdx.x % nblk;
  int i = wb * 1024 + tid;
  int v = (i < n) ? deg4[(size_t)layer * n + i] + 1 : 0;   // +1 self-loop
  buf[tid] = v;
  __syncthreads();
#pragma unroll
  for (int d = 1; d < 1024; d <<= 1) {
    int t = (tid >= d) ? buf[tid - d] : 0;
    __syncthreads();
    buf[tid] += t;
    __syncthreads();
  }
  if (i < n) incl4[(size_t)layer * n + i] = buf[tid];
  if (tid == 1023) bsum[blockIdx.x] = buf[1023];
}

__global__ __launch_bounds__(128) void scan_phase2(
    int* __restrict__ bsum, int nb, int* __restrict__ offs4, int n)
{
  __shared__ int buf[128];
  int l = blockIdx.x, tid = threadIdx.x;
  int v = (tid < nb) ? bsum[l * nb + tid] : 0;
  buf[tid] = v;
  __syncthreads();
#pragma unroll
  for (int d = 1; d < 128; d <<= 1) {
    int t = (tid >= d) ? buf[tid - d] : 0;
    __syncthreads();
    buf[tid] += t;
    __syncthreads();
  }
  if (tid < nb) bsum[l * nb + tid] = buf[tid] - v;   // exclusive
  if (tid == 127) offs4[(size_t)l * (n + 1) + n] = buf[127];
}

__global__ __launch_bounds__(256) void scan_phase3(
    const int* __restrict__ incl4, const int* __restrict__ deg4,
    const int* __restrict__ bsum, int* __restrict__ offs4,
    int* __restrict__ cur4, int n, int nb, int nb3)
{
  int l = blockIdx.x / nb3;
  int i = (blockIdx.x % nb3) * 256 + threadIdx.x;
  if (i >= n) return;
  int v = deg4[(size_t)l * n + i] + 1;
  int e = incl4[(size_t)l * n + i] - v + bsum[l * nb + (i >> 10)];
  offs4[(size_t)l * (n + 1) + i] = e;
  cur4[(size_t)l * n + i] = e;
}

__global__ __launch_bounds__(256) void fill_all_kernel(
    const int* __restrict__ s0, const int* __restrict__ s1,
    const int* __restrict__ s2, const int* __restrict__ s3,
    const int* __restrict__ d0, const int* __restrict__ d1,
    const int* __restrict__ d2, const int* __restrict__ d3,
    int e0, int e1, int e2, int e3, int n,
    int* __restrict__ cur4, int* __restrict__ csr4,
    int cb0, int cb1, int cb2, int cb3)
{
  int id = blockIdx.x * 256 + threadIdx.x;
  int t1 = e0, t2 = t1 + e1, t3 = t2 + e2, t4 = t3 + e3;
  if (id >= t4 + 4 * n) return;
  int l, s, d;
  if (id < t4) {
    const int *sp, *dp; int e;
    if      (id < t1) { l = 0; e = id;      sp = s0; dp = d0; }
    else if (id < t2) { l = 1; e = id - t1; sp = s1; dp = d1; }
    else if (id < t3) { l = 2; e = id - t2; sp = s2; dp = d2; }
    else              { l = 3; e = id - t3; sp = s3; dp = d3; }
    s = sp[e]; d = dp[e];
  } else {
    int k = id - t4;
    l = (k >= 3 * n) ? 3 : (k >= 2 * n) ? 2 : (k >= n) ? 1 : 0;
    s = k - l * n; d = s;                     // self-loop
  }
  int slot = atomicAdd(&cur4[(size_t)l * n + d], 1);
  int cb = (l == 0) ? cb0 : (l == 1) ? cb1 : (l == 2) ? cb2 : cb3;
  csr4[cb + slot] = s;
}

// ---------------- fused GATv2 edge phase -----------------------------------
// One wave per dst node; 4 subgroups of 16 lanes each handle one edge per
// iteration; lane handles 8 dims (one bf16x8 = 16B load per edge).
// Single-pass softmax (logits O(30), exp can't overflow fp32).
__global__ __launch_bounds__(256) void gat_dst_kernel(
    const unsigned short* __restrict__ xlb,
    const unsigned short* __restrict__ xrb,
    const int* __restrict__ offs, const int* __restrict__ csr,
    const float* __restrict__ att, const float* __restrict__ bias,
    float* __restrict__ hout_f, unsigned short* __restrict__ hout_b, int n)
{
  int wid  = (blockIdx.x * 256 + threadIdx.x) >> 6;
  int lane = threadIdx.x & 63;
  if (wid >= n) return;
  int g = lane >> 4;          // subgroup 0..3 (edge slot)
  int c = lane & 15;          // dim chunk: dims c*8 .. c*8+7

  bf16x8 xr8 = *(const bf16x8*)(xrb + (size_t)wid * 128 + c * 8);
  float xrv[8], a[8];
#pragma unroll
  for (int k = 0; k < 8; ++k) { xrv[k] = bf2f(xr8[k]); a[k] = att[c * 8 + k]; }

  int beg = offs[wid], end = offs[wid + 1];
  float ssum = 0.f, acc[8];
#pragma unroll
  for (int k = 0; k < 8; ++k) acc[k] = 0.f;

  for (int j0 = beg; j0 < end; j0 += 4) {
    int j  = j0 + g;
    int jj = (j < end) ? j : end - 1;        // degree>=1 (self-loop)
    int s  = csr[jj];
    bf16x8 xs8 = *(const bf16x8*)(xlb + (size_t)s * 128 + c * 8);
    float xs[8];
#pragma unroll
    for (int k = 0; k < 8; ++k) xs[k] = bf2f(xs8[k]);
    float part = 0.f;
#pragma unroll
    for (int k = 0; k < 8; ++k) {
      float t = xs[k] + xrv[k];
      t = (t > 0.f) ? t : 0.2f * t;
      part = fmaf(t, a[k], part);
    }
    part += __shfl_xor(part, 1, 64);
    part += __shfl_xor(part, 2, 64);
    part += __shfl_xor(part, 4, 64);
    part += __shfl_xor(part, 8, 64);
    float p = (j < end) ? __expf(part) : 0.f;
    ssum += p;
#pragma unroll
    for (int k = 0; k < 8; ++k) acc[k] = fmaf(p, xs[k], acc[k]);
  }
  // combine subgroup partials (butterfly over lanes 16, 32)
#pragma unroll
  for (int k = 0; k < 8; ++k) {
    acc[k] += __shfl_xor(acc[k], 16, 64);
    acc[k] += __shfl_xor(acc[k], 32, 64);
  }
  ssum += __shfl_xor(ssum, 16, 64);
  ssum += __shfl_xor(ssum, 32, 64);

  float inv = 1.0f / ssum;
  float o[8];
#pragma unroll
  for (int k = 0; k < 8; ++k) o[k] = fmaf(acc[k], inv, bias[c * 8 + k]);

  if (lane < 16) {
    if (hout_f) {
      float4 v0 = make_float4(o[0], o[1], o[2], o[3]);
      float4 v1 = make_float4(o[4], o[5], o[6], o[7]);
      *(float4*)(hout_f + (size_t)wid * 128 + c * 8)     = v0;
      *(float4*)(hout_f + (size_t)wid * 128 + c * 8 + 4) = v1;
    } else {
      bf16x8 ob;
#pragma unroll
      for (int k = 0; k < 8; ++k) ob[k] = (short)f2bf(o[k]);
      *(bf16x8*)(hout_b + (size_t)wid * 128 + c * 8) = ob;
    }
  }
}

// ---------------- pooling + output GEMM ------------------------------------
__global__ __launch_bounds__(256) void pool_kernel(
    const float* __restrict__ h, const int* __restrict__ gnode,
    const int* __restrict__ bidx, float* __restrict__ pooled, int ng)
{
  __shared__ float acc[64 * 128];           // 32 KiB
  int tid = threadIdx.x;
  for (int t = tid; t < 64 * 128; t += 256) acc[t] = 0.f;
  __syncthreads();
  int col = tid & 127, half = tid >> 7;
  for (int nd = blockIdx.x * 2 + half; nd < ng; nd += gridDim.x * 2) {
    int row = gnode[nd];
    int g   = bidx[nd];
    atomicAdd(&acc[g * 128 + col], h[(size_t)row * 128 + col]);
  }
  __syncthreads();
  for (int t = tid; t < 64 * 128; t += 256) atomicAdd(&pooled[t], acc[t]);
}

__global__ __launch_bounds__(256) void out_gemm_kernel(
    const float* __restrict__ pooled, const float* __restrict__ W,
    const float* __restrict__ b, float* __restrict__ out)
{
  int id = blockIdx.x * 256 + threadIdx.x;
  if (id >= 64 * 16) return;
  int g = id >> 4, f = id & 15;
  float acc = b[f];
#pragma unroll
  for (int k = 0; k < 128; ++k)
    acc += pooled[g * 128 + k] * W[k * 16 + f];
  out[id] = acc;
}

// ---------------------------------------------------------------------------
extern "C" void kernel_launch(void* const* d_in, const int* in_sizes, int n_in,
                              void* d_out, int out_size, void* d_ws, size_t ws_size,
                              hipStream_t stream)
{
  const float* x    = (const float*)d_in[0];
  const int* ei0    = (const int*)d_in[1];   // edge_index            [2,1e6]
  const int* ei_sg  = (const int*)d_in[2];   // subgraph_edge_index   [2,1e6]
  const int* ei_ns  = (const int*)d_in[3];   // node_subnode_index    [2,2e5]
  const int* ei_sn  = (const int*)d_in[4];   // subnode_node_index    [2,2e5]
  const int* gnode  = (const int*)d_in[5];   // ground_node
  // d_in[6] = subgraph_batch_index (unused by reference)
  const int* bidx   = (const int*)d_in[7];   // batch_idx
  const float* embW = (const float*)d_in[8];
  const float* embB = (const float*)d_in[9];
  const float* Wl   = (const float*)d_in[10];
  const float* Wr   = (const float*)d_in[11];
  const float* att  = (const float*)d_in[12];
  const float* bias = (const float*)d_in[13];
  const float* outW = (const float*)d_in[14];
  const float* outB = (const float*)d_in[15];

  const int n  = in_sizes[0] / 32;           // 100000
  const int ng = in_sizes[5];                // 40000

  // reference layer order: edge_index, node_subnode, subgraph_edge, subnode_node
  const int  E_arr[4] = { in_sizes[1] / 2, in_sizes[3] / 2,
                          in_sizes[2] / 2, in_sizes[4] / 2 };
  const int* eptr[4]  = { ei0, ei_ns, ei_sg, ei_sn };
  const int E_tot = E_arr[0] + E_arr[1] + E_arr[2] + E_arr[3];
  // CSR bases (each layer: E_l + n slots)
  int cb[4];
  cb[0] = 0;
  for (int i = 1; i < 4; ++i) cb[i] = cb[i - 1] + E_arr[i - 1] + n;

  // workspace carve (bump allocator, 256B aligned)
  char* ws = (char*)d_ws;
  size_t off = 0;
  auto alloc = [&](size_t bytes) -> void* {
    void* p = ws + off;
    off = (off + bytes + 255) & ~(size_t)255;
    return p;
  };
  float*          h      = (float*)alloc((size_t)n * 128 * sizeof(float));
  unsigned short* hb     = (unsigned short*)alloc((size_t)n * 128 * sizeof(unsigned short));
  unsigned short* xlb    = (unsigned short*)alloc((size_t)n * 128 * sizeof(unsigned short));
  unsigned short* xrb    = (unsigned short*)alloc((size_t)n * 128 * sizeof(unsigned short));
  int*            deg4   = (int*)alloc((size_t)4 * n * sizeof(int));
  int*            incl4  = (int*)alloc((size_t)4 * n * sizeof(int));
  int*            offs4  = (int*)alloc((size_t)4 * (n + 1) * sizeof(int));
  int*            cur4   = (int*)alloc((size_t)4 * n * sizeof(int));
  int*            bsum   = (int*)alloc(4 * 128 * sizeof(int));
  int*            csr4   = (int*)alloc((size_t)(E_tot + 4 * n) * sizeof(int));
  unsigned short* packB  = (unsigned short*)alloc(131072 * sizeof(unsigned short));
  float*          pooled = (float*)alloc(64 * 128 * sizeof(float));
  (void)ws_size; (void)n_in; (void)out_size;

  const int nb  = (n + 1023) / 1024;         // scan blocks per layer (98)
  const int nb3 = (n + 255) / 256;

  // dst rows of each edge list
  const int* D[4] = { eptr[0] + E_arr[0], eptr[1] + E_arr[1],
                      eptr[2] + E_arr[2], eptr[3] + E_arr[3] };

  int setup_items = 131072 + 4 * n + 64 * 128;
  setup_kernel<<<(setup_items + 255) / 256, 256, 0, stream>>>(
      Wl, Wr, packB, deg4, pooled, n);
  embed_gemm_kernel<<<(n + 1) / 2, 256, 0, stream>>>(x, embW, embB, hb, n);

  // batched CSR build for all 4 graphs
  count_all_kernel<<<(E_tot + 255) / 256, 256, 0, stream>>>(
      D[0], D[1], D[2], D[3], E_arr[0], E_arr[1], E_arr[2], E_arr[3], n, deg4);
  scan_phase1<<<4 * nb, 1024, 0, stream>>>(deg4, incl4, bsum, n, nb);
  scan_phase2<<<4, 128, 0, stream>>>(bsum, nb, offs4, n);
  scan_phase3<<<4 * nb3, 256, 0, stream>>>(incl4, deg4, bsum, offs4, cur4, n, nb, nb3);
  fill_all_kernel<<<(E_tot + 4 * n + 255) / 256, 256, 0, stream>>>(
      eptr[0], eptr[1], eptr[2], eptr[3], D[0], D[1], D[2], D[3],
      E_arr[0], E_arr[1], E_arr[2], E_arr[3], n, cur4, csr4,
      cb[0], cb[1], cb[2], cb[3]);

  for (int l = 0; l < 4; ++l) {
    gemm_mfma_kernel<<<1024, 256, 0, stream>>>(
        hb, packB + (size_t)l * 32768, xlb, xrb, n);
    gat_dst_kernel<<<((size_t)n * 64 + 255) / 256, 256, 0, stream>>>(
        xlb, xrb, offs4 + (size_t)l * (n + 1), csr4 + cb[l],
        att + (size_t)l * 128, bias + (size_t)l * 128,
        (l == 3) ? h : nullptr, (l < 3) ? hb : nullptr, n);
  }

  pool_kernel<<<64, 256, 0, stream>>>(h, gnode, bidx, pooled, ng);
  out_gemm_kernel<<<4, 256, 0, stream>>>(pooled, outW, outB, (float*)d_out);
}